// Round 14
// baseline (131.697 us; speedup 1.0000x reference)
//
#include <hip/hip_runtime.h>
#include <hip/hip_bf16.h>

// ---------------- problem constants ----------------
constexpr int Bq = 16384;   // batch
constexpr int Cc = 256;     // hidden
constexpr int Ss = 40;      // prev/out width

// ---------------- ws layout (bytes) ----------------
constexpr size_t O_W1P  = 0;          // bf16 packed d1 W: 20 slabs x 8KB = 160KB
constexpr size_t O_W2P  = 0x28000;    // bf16 packed d2 W: 16 slabs x 8KB = 128KB
constexpr size_t O_WOUT = 0x48000;    // bf16 [128][256] linear, 64KB
constexpr size_t O_WGF1 = 0x60000;    // bf16 packed gate W, 768KB (32 slabs x 24KB)
constexpr size_t O_WGF2 = 0x120000;
constexpr size_t O_WGF3 = 0x1E0000;
constexpr size_t O_BD1  = 0x2A0000;   // f32 [256]
constexpr size_t O_BD2  = 0x2A0400;   // f32 [256]
constexpr size_t O_BOUT = 0x2A0800;   // f32 [128] (pad 0)
constexpr size_t O_BG1  = 0x2A1000;   // f32 [1024]: [0..511]=b_ih+b_hh (r,z), [512..767]=b_ih_n, [768..1023]=b_hh_n
constexpr size_t O_BG2  = 0x2A2000;
constexpr size_t O_BG3  = 0x2A3000;
constexpr size_t O_XMLP = 0x2B0000;   // bf16 [B][256] 8MB (dense2 out)
constexpr size_t O_GB1  = 0xAB0000;   // bf16 [B][256]  (g1)
constexpr size_t O_GB2  = 0x12B0000;  // bf16 [B][256]  (g2)
constexpr size_t O_GB3  = 0x1AB0000;  // bf16 [B][256]  (g3, head input)
constexpr size_t O_HB1  = 0x22B0000;  // bf16 [B][256]  (h bf16, written by prep)
constexpr size_t O_HB2  = 0x2AB0000;
constexpr size_t O_HB3  = 0x32B0000;
constexpr size_t O_T1   = 0x3AB0000;  // bf16 [B][256]  (dense1 out)

// d_out element offsets (fp32): out[B,40], g1[B,256], g2, g3
constexpr size_t GO_OUT = 0;
constexpr size_t GO_G1  = (size_t)Bq * Ss;
constexpr size_t GO_G2  = GO_G1 + (size_t)Bq * Cc;
constexpr size_t GO_G3  = GO_G2 + (size_t)Bq * Cc;

typedef __attribute__((ext_vector_type(8))) short bf16x8;
typedef __attribute__((ext_vector_type(4))) float f32x4;

__device__ __forceinline__ float bf2f(unsigned short h) {
    union { unsigned u; float f; } v; v.u = ((unsigned)h) << 16; return v.f;
}
__device__ __forceinline__ unsigned short f2bf(float f) {
    union { float f; unsigned u; } v; v.f = f;
    unsigned u = v.u;
    return (unsigned short)((u + 0x7FFFu + ((u >> 16) & 1u)) >> 16);
}
__device__ __forceinline__ float sigf(float x) { return 1.f / (1.f + __expf(-x)); }

__device__ __forceinline__ bf16x8 cvt8(const float* __restrict__ s) {
    float4 a = *(const float4*)s;
    float4 b = *(const float4*)(s + 4);
    bf16x8 o;
    o[0] = (short)f2bf(a.x); o[1] = (short)f2bf(a.y);
    o[2] = (short)f2bf(a.z); o[3] = (short)f2bf(a.w);
    o[4] = (short)f2bf(b.x); o[5] = (short)f2bf(b.y);
    o[6] = (short)f2bf(b.z); o[7] = (short)f2bf(b.w);
    return o;
}

// ---------------- prep: weights + biases + h->bf16 (streaming, high-occ) ----
constexpr long U_W1P = 20L * 512;       // 10240 chunks (4 cb x 5 kt)
constexpr long U_W2P = 16L * 512;       //  8192 (4 cb x 4 kt)
constexpr long NWGF  = 768L * 512;      // per-GRU gate elems
constexpr long U_WG  = 3 * NWGF / 8;    // 147456
constexpr long U_WO  = 128L * 256 / 8;  // 4096 (linear Wout)
constexpr long NBIA  = 256 + 256 + 128 + 3L * 1024;  // 3712
constexpr long U_B   = (NBIA + 7) / 8;  // 464
constexpr long NH    = (long)Bq * Cc;   // per h
constexpr long U_H   = 3 * NH / 8;      // 1572864
constexpr long U_TOT = U_H + U_W1P + U_W2P + U_WG + U_WO + U_B;

__global__ void prep_w(
    const float* __restrict__ h1, const float* __restrict__ h2, const float* __restrict__ h3,
    const float* __restrict__ w_d1, const float* __restrict__ b_d1,
    const float* __restrict__ w_d2, const float* __restrict__ b_d2,
    const float* __restrict__ w_ih1, const float* __restrict__ w_hh1,
    const float* __restrict__ b_ih1, const float* __restrict__ b_hh1,
    const float* __restrict__ w_ih2, const float* __restrict__ w_hh2,
    const float* __restrict__ b_ih2, const float* __restrict__ b_hh2,
    const float* __restrict__ w_ih3, const float* __restrict__ w_hh3,
    const float* __restrict__ b_ih3, const float* __restrict__ b_hh3,
    const float* __restrict__ w_out, const float* __restrict__ b_out,
    char* __restrict__ ws)
{
    long v = (long)blockIdx.x * blockDim.x + threadIdx.x;
    if (v >= U_TOT) return;
    if (v < U_H) {  // h1..h3 -> bf16 (biggest section first, perfect coalescing)
        int g = (int)(v / (NH / 8)); long r8 = v % (NH / 8);
        long e = r8 * 8;
        const float* hp = (g == 0) ? h1 : (g == 1) ? h2 : h3;
        size_t off = (g == 0) ? O_HB1 : (g == 1) ? O_HB2 : O_HB3;
        *(bf16x8*)((unsigned short*)(ws + off) + e) = cvt8(hp + e);
        return;
    }
    v -= U_H;
    if (v < U_W1P) {  // d1 slabs: p = cb*5+kt; src [256][296]
        int sseg = (int)(v & 7), wrow = (int)((v >> 3) & 63), p = (int)(v >> 9);
        int kt = p % 5, cb = p / 5;
        int n = cb * 64 + wrow;
        int k = kt * 64 + ((sseg ^ (wrow & 7)) << 3);
        bf16x8 o = {0,0,0,0,0,0,0,0};
        if (k < 296) o = cvt8(w_d1 + (long)n * 296 + k);
        *(bf16x8*)((unsigned short*)(ws + O_W1P) + v * 8) = o;
        return;
    }
    v -= U_W1P;
    if (v < U_W2P) {  // d2 slabs: p = cb*4+kt
        int sseg = (int)(v & 7), wrow = (int)((v >> 3) & 63), p = (int)(v >> 9);
        int kt = p & 3, cb = p >> 2;
        int n = cb * 64 + wrow;
        int k = kt * 64 + ((sseg ^ (wrow & 7)) << 3);
        *(bf16x8*)((unsigned short*)(ws + O_W2P) + v * 8) = cvt8(w_d2 + (long)n * 256 + k);
        return;
    }
    v -= U_W2P;
    if (v < U_WG) {  // gate slabs: p = cb*8+kt, s-stacked
        int g = (int)(v / (NWGF / 8)); long vv = v % (NWGF / 8);
        int sseg = (int)(vv & 7);
        int wrow = (int)((vv >> 3) & 63);
        long q = vv >> 9;
        int s = (int)(q % 3);
        long p = q / 3;
        int ktt = (int)(p & 7), cb = (int)(p >> 3);
        int n = s * 256 + cb * 64 + wrow;
        int k = ktt * 64 + ((sseg ^ (wrow & 7)) << 3);
        const float* wih = (g == 0) ? w_ih1 : (g == 1) ? w_ih2 : w_ih3;
        const float* whh = (g == 0) ? w_hh1 : (g == 1) ? w_hh2 : w_hh3;
        size_t off = (g == 0) ? O_WGF1 : (g == 1) ? O_WGF2 : O_WGF3;
        const float* src = (k < 256) ? (wih + (long)n * 256 + k)
                                     : (whh + (long)n * 256 + (k - 256));
        *(bf16x8*)((unsigned short*)(ws + off) + vv * 8) = cvt8(src);
        return;
    }
    v -= U_WG;
    if (v < U_WO) {  // Wout [128][256] linear, rows >= 40 zero
        long e = v * 8;
        int n = (int)(e / 256);
        bf16x8 o = {0,0,0,0,0,0,0,0};
        if (n < Ss) o = cvt8(w_out + e);
        *(bf16x8*)((unsigned short*)(ws + O_WOUT) + e) = o;
        return;
    }
    v -= U_WO;
    {   // biases, scalar
        long ebase = v * 8;
#pragma unroll
        for (int t = 0; t < 8; ++t) {
            long j = ebase + t;
            if (j >= NBIA) break;
            if (j < 256) { ((float*)(ws + O_BD1))[j] = b_d1[j]; continue; }
            long j2 = j - 256;
            if (j2 < 256) { ((float*)(ws + O_BD2))[j2] = b_d2[j2]; continue; }
            j2 -= 256;
            if (j2 < 128) { ((float*)(ws + O_BOUT))[j2] = (j2 < Ss) ? b_out[j2] : 0.f; continue; }
            j2 -= 128;
            int g = (int)(j2 / 1024); int jj = (int)(j2 % 1024);
            const float* bih = (g == 0) ? b_ih1 : (g == 1) ? b_ih2 : b_ih3;
            const float* bhh = (g == 0) ? b_hh1 : (g == 1) ? b_hh2 : b_hh3;
            float* dst = (float*)(ws + ((g == 0) ? O_BG1 : (g == 1) ? O_BG2 : O_BG3));
            float val;
            if (jj < 512)      val = bih[jj] + bhh[jj];
            else if (jj < 768) val = bih[jj];           // b_ih_n
            else               val = bhh[jj - 256];     // b_hh_n
            dst[jj] = val;
        }
    }
}

// ---------------- d1: tanh([cond|prev] @ Wd1^T + b1) -> t1 (pure GEMM) ------
// Tile 256x64, grid (64,4), 512 thr (waves 4Mx2N). A converted in-regs and
// ds_written position-linear w/ content-XOR; W via gload_lds packed slabs.
__launch_bounds__(512, 2)
__global__ void d1_gemm(const float* __restrict__ cond, const float* __restrict__ prev,
                        const unsigned short* __restrict__ W1P,
                        const float* __restrict__ B1,
                        unsigned short* __restrict__ t1)
{
    __shared__ __align__(16) unsigned short sA[2][256 * 64];   // 2 x 32KB
    __shared__ __align__(16) unsigned short sW[2][64 * 64];    // 2 x 8KB

    const int tid  = threadIdx.x;
    const int lane = tid & 63;
    const int wid  = tid >> 6;
    const int wm   = wid >> 1, wn = wid & 1;
    const int g4   = lane >> 4, lc = lane & 15;
    const long brow = (long)blockIdx.x * 256;
    const int  by   = blockIdx.y;

    f32x4 acc[4][2];
#pragma unroll
    for (int i = 0; i < 4; i++)
#pragma unroll
        for (int j = 0; j < 2; j++) acc[i][j] = (f32x4){0.f,0.f,0.f,0.f};

    float4 areg[8];
    auto issue_a = [&](int kt) {   // load kt-slice of [cond|prev|0]
#pragma unroll
        for (int i = 0; i < 4; ++i) {
            const int c = i * 512 + tid;
            const int row = c >> 3;
            const int segl = (c & 7) ^ (row & 7);
            const int col = kt * 64 + segl * 8;
            if (kt < 4) {
                const float* s = cond + (brow + row) * 256 + col;
                areg[2 * i]     = *(const float4*)s;
                areg[2 * i + 1] = *(const float4*)(s + 4);
            } else {
                if (segl < 5) {
                    const float* s = prev + (brow + row) * Ss + (col - 256);
                    areg[2 * i]     = *(const float4*)s;
                    areg[2 * i + 1] = *(const float4*)(s + 4);
                } else {
                    areg[2 * i]     = make_float4(0.f, 0.f, 0.f, 0.f);
                    areg[2 * i + 1] = make_float4(0.f, 0.f, 0.f, 0.f);
                }
            }
        }
    };
    auto write_a = [&](int buf) {
#pragma unroll
        for (int i = 0; i < 4; ++i) {
            const int c = i * 512 + tid;
            const float4 a = areg[2 * i], b = areg[2 * i + 1];
            bf16x8 o;
            o[0] = (short)f2bf(a.x); o[1] = (short)f2bf(a.y);
            o[2] = (short)f2bf(a.z); o[3] = (short)f2bf(a.w);
            o[4] = (short)f2bf(b.x); o[5] = (short)f2bf(b.y);
            o[6] = (short)f2bf(b.z); o[7] = (short)f2bf(b.w);
            *(bf16x8*)(&sA[buf][0] + (size_t)c * 8) = o;
        }
    };
    auto stage_w = [&](int buf, int kt) {  // 8KB slab, 1 chunk/thread
        const unsigned short* Wbase = W1P + (size_t)(by * 5 + kt) * 4096;
        __builtin_amdgcn_global_load_lds(
            (const __attribute__((address_space(1))) void*)(Wbase + (size_t)tid * 8),
            (__attribute__((address_space(3))) void*)(&sW[buf][0] + (size_t)tid * 8), 16, 0, 0);
    };

    // prologue
    issue_a(0);
    stage_w(0, 0);
    write_a(0);
    __syncthreads();

#pragma unroll
    for (int kt = 0; kt < 5; ++kt) {
        const int cur = kt & 1;
        if (kt < 4) { issue_a(kt + 1); stage_w(cur ^ 1, kt + 1); }

#pragma unroll
        for (int kk = 0; kk < 2; ++kk) {
            bf16x8 af[4], wf[2];
#pragma unroll
            for (int mf = 0; mf < 4; ++mf) {
                const int row = wm * 64 + mf * 16 + lc;
                const int chunk = row * 8 + ((kk * 4 + g4) ^ (row & 7));
                af[mf] = *(const bf16x8*)&sA[cur][chunk * 8];
            }
#pragma unroll
            for (int nf = 0; nf < 2; ++nf) {
                const int wrow = wn * 32 + nf * 16 + lc;
                const int chunk = wrow * 8 + ((kk * 4 + g4) ^ (wrow & 7));
                wf[nf] = *(const bf16x8*)&sW[cur][chunk * 8];
            }
            __builtin_amdgcn_s_setprio(1);
#pragma unroll
            for (int mf = 0; mf < 4; ++mf)
#pragma unroll
                for (int nf = 0; nf < 2; ++nf)
                    acc[mf][nf] = __builtin_amdgcn_mfma_f32_16x16x32_bf16(af[mf], wf[nf], acc[mf][nf], 0, 0, 0);
            __builtin_amdgcn_s_setprio(0);
        }
        if (kt < 4) write_a(cur ^ 1);
        __syncthreads();
    }

    // epilogue: tanh -> t1
    const int lr4 = g4 * 4;
#pragma unroll
    for (int mf = 0; mf < 4; ++mf)
#pragma unroll
        for (int nf = 0; nf < 2; ++nf) {
            const int col = by * 64 + wn * 32 + nf * 16 + lc;
            const float bs = B1[col];
#pragma unroll
            for (int j = 0; j < 4; ++j) {
                const long r = brow + wm * 64 + mf * 16 + lr4 + j;
                t1[r * 256 + col] = f2bf(tanhf(acc[mf][nf][j] + bs));
            }
        }
}

// ---------------- d2: tanh(t1 @ Wd2^T + b2) -> XMLP ----------------
__launch_bounds__(512, 2)
__global__ void d2_gemm(const unsigned short* __restrict__ t1,
                        const unsigned short* __restrict__ W2P,
                        const float* __restrict__ B2,
                        unsigned short* __restrict__ xout)
{
    __shared__ __align__(16) unsigned short sA[2][256 * 64];   // 2 x 32KB
    __shared__ __align__(16) unsigned short sW[2][64 * 64];    // 2 x 8KB

    const int tid  = threadIdx.x;
    const int lane = tid & 63;
    const int wid  = tid >> 6;
    const int wm   = wid >> 1, wn = wid & 1;
    const int g4   = lane >> 4, lc = lane & 15;
    const long brow = (long)blockIdx.x * 256;
    const int  by   = blockIdx.y;

    f32x4 acc[4][2];
#pragma unroll
    for (int i = 0; i < 4; i++)
#pragma unroll
        for (int j = 0; j < 2; j++) acc[i][j] = (f32x4){0.f,0.f,0.f,0.f};

    auto stage_a = [&](int buf, int kt) {
#pragma unroll
        for (int i = 0; i < 4; ++i) {
            const int c = i * 512 + tid;
            const int row = c >> 3;
            const int kcol = ((c & 7) ^ (row & 7)) << 3;
            const unsigned short* ga = t1 + (brow + row) * 256 + kt * 64 + kcol;
            __builtin_amdgcn_global_load_lds(
                (const __attribute__((address_space(1))) void*)ga,
                (__attribute__((address_space(3))) void*)(&sA[buf][0] + (size_t)c * 8), 16, 0, 0);
        }
    };
    auto stage_w = [&](int buf, int kt) {
        const unsigned short* Wbase = W2P + (size_t)(by * 4 + kt) * 4096;
        __builtin_amdgcn_global_load_lds(
            (const __attribute__((address_space(1))) void*)(Wbase + (size_t)tid * 8),
            (__attribute__((address_space(3))) void*)(&sW[buf][0] + (size_t)tid * 8), 16, 0, 0);
    };

    stage_a(0, 0);
    stage_w(0, 0);
    __syncthreads();

#pragma unroll
    for (int kt = 0; kt < 4; ++kt) {
        const int cur = kt & 1;
        if (kt < 3) { stage_a(cur ^ 1, kt + 1); stage_w(cur ^ 1, kt + 1); }

#pragma unroll
        for (int kk = 0; kk < 2; ++kk) {
            bf16x8 af[4], wf[2];
#pragma unroll
            for (int mf = 0; mf < 4; ++mf) {
                const int row = wm * 64 + mf * 16 + lc;
                const int chunk = row * 8 + ((kk * 4 + g4) ^ (row & 7));
                af[mf] = *(const bf16x8*)&sA[cur][chunk * 8];
            }
#pragma unroll
            for (int nf = 0; nf < 2; ++nf) {
                const int wrow = wn * 32 + nf * 16 + lc;
                const int chunk = wrow * 8 + ((kk * 4 + g4) ^ (wrow & 7));
                wf[nf] = *(const bf16x8*)&sW[cur][chunk * 8];
            }
            __builtin_amdgcn_s_setprio(1);
#pragma unroll
            for (int mf = 0; mf < 4; ++mf)
#pragma unroll
                for (int nf = 0; nf < 2; ++nf)
                    acc[mf][nf] = __builtin_amdgcn_mfma_f32_16x16x32_bf16(af[mf], wf[nf], acc[mf][nf], 0, 0, 0);
            __builtin_amdgcn_s_setprio(0);
        }
        __syncthreads();
    }

    const int lr4 = g4 * 4;
#pragma unroll
    for (int mf = 0; mf < 4; ++mf)
#pragma unroll
        for (int nf = 0; nf < 2; ++nf) {
            const int col = by * 64 + wn * 32 + nf * 16 + lc;
            const float bs = B2[col];
#pragma unroll
            for (int j = 0; j < 4; ++j) {
                const long r = brow + wm * 64 + mf * 16 + lr4 + j;
                xout[r * 256 + col] = f2bf(tanhf(acc[mf][nf][j] + bs));
            }
        }
}

// ---------------- fused GRU v7 (best known, unchanged) ----------------
__launch_bounds__(512, 1)
__global__ void gru_fused(const unsigned short* __restrict__ x,
                          const unsigned short* __restrict__ hb,
                          const unsigned short* __restrict__ PW,
                          const float* __restrict__ BG,
                          float* __restrict__ gout,
                          unsigned short* __restrict__ actout)
{
    __shared__ __align__(16) unsigned short sA[2][256 * 64];     // 2 x 32KB
    __shared__ __align__(16) unsigned short sW[3][3 * 64 * 64];  // 3 x 24KB

    const int tid  = threadIdx.x;
    const int lane = tid & 63;
    const int wid  = tid >> 6;        // 0..7
    const int wm   = wid >> 1;        // 0..3: 64-row strip
    const int wn   = wid & 1;         // 0..1: 32-col half
    const int g4   = lane >> 4;       // 0..3 (k-segment group)
    const int lc   = lane & 15;
    const long brow = (long)blockIdx.x * 256;
    const int  by   = blockIdx.y;     // col block (64 cols)
    const int  c0   = by * 64;

    f32x4 accR[4][2], accZ[4][2], accI[4][2], accH[4][2];
#pragma unroll
    for (int i = 0; i < 4; i++)
#pragma unroll
        for (int j = 0; j < 2; j++) {
            accR[i][j] = (f32x4){0.f,0.f,0.f,0.f};
            accZ[i][j] = (f32x4){0.f,0.f,0.f,0.f};
            accI[i][j] = (f32x4){0.f,0.f,0.f,0.f};
            accH[i][j] = (f32x4){0.f,0.f,0.f,0.f};
        }

    auto stage_a = [&](int buf, int kt) {
        const unsigned short* src = (kt < 4) ? x : hb;
        const int kc0 = (kt & 3) * 64;
#pragma unroll
        for (int i = 0; i < 4; ++i) {
            const int c = i * 512 + tid;
            const int row = c >> 3;
            const int kcol = ((c & 7) ^ (row & 7)) << 3;
            const unsigned short* ga = src + (brow + row) * 256 + kc0 + kcol;
            __builtin_amdgcn_global_load_lds(
                (const __attribute__((address_space(1))) void*)ga,
                (__attribute__((address_space(3))) void*)(&sA[buf][0] + (size_t)c * 8), 16, 0, 0);
        }
    };
    auto stage_w = [&](int buf, int kt) {
        const unsigned short* Wbase = PW + (size_t)(by * 8 + kt) * 12288;
#pragma unroll
        for (int i = 0; i < 3; ++i) {
            const int c = i * 512 + tid;
            const unsigned short* gw = Wbase + (size_t)c * 8;
            __builtin_amdgcn_global_load_lds(
                (const __attribute__((address_space(1))) void*)gw,
                (__attribute__((address_space(3))) void*)(&sW[buf][0] + (size_t)c * 8), 16, 0, 0);
        }
    };

    stage_w(0, 0);
    stage_a(0, 0);
    stage_w(1, 1);

#pragma unroll
    for (int kt = 0; kt < 8; ++kt) {
        if (kt < 7) asm volatile("s_waitcnt vmcnt(3)" ::: "memory");
        else        asm volatile("s_waitcnt vmcnt(0)" ::: "memory");
        __builtin_amdgcn_s_barrier();
        __builtin_amdgcn_sched_barrier(0);

        if (kt + 1 < 8) stage_a((kt + 1) & 1, kt + 1);
        if (kt + 2 < 8) stage_w((kt + 2) % 3, kt + 2);

        const int ab = kt & 1, wb = kt % 3;
#pragma unroll
        for (int kk = 0; kk < 2; ++kk) {
            bf16x8 af[4], wf[3][2];
#pragma unroll
            for (int mf = 0; mf < 4; ++mf) {
                const int row = wm * 64 + mf * 16 + lc;
                const int chunk = row * 8 + ((kk * 4 + g4) ^ (row & 7));
                af[mf] = *(const bf16x8*)&sA[ab][chunk * 8];
            }
#pragma unroll
            for (int s = 0; s < 3; ++s)
#pragma unroll
                for (int nf = 0; nf < 2; ++nf) {
                    const int wrow = wn * 32 + nf * 16 + lc;
                    const int chunk = s * 512 + wrow * 8 + ((kk * 4 + g4) ^ (wrow & 7));
                    wf[s][nf] = *(const bf16x8*)&sW[wb][chunk * 8];
                }
            __builtin_amdgcn_s_setprio(1);
            if (kt < 4) {
#pragma unroll
                for (int mf = 0; mf < 4; ++mf)
#pragma unroll
                    for (int nf = 0; nf < 2; ++nf) {
                        accR[mf][nf] = __builtin_amdgcn_mfma_f32_16x16x32_bf16(af[mf], wf[0][nf], accR[mf][nf], 0, 0, 0);
                        accZ[mf][nf] = __builtin_amdgcn_mfma_f32_16x16x32_bf16(af[mf], wf[1][nf], accZ[mf][nf], 0, 0, 0);
                        accI[mf][nf] = __builtin_amdgcn_mfma_f32_16x16x32_bf16(af[mf], wf[2][nf], accI[mf][nf], 0, 0, 0);
                    }
            } else {
#pragma unroll
                for (int mf = 0; mf < 4; ++mf)
#pragma unroll
                    for (int nf = 0; nf < 2; ++nf) {
                        accR[mf][nf] = __builtin_amdgcn_mfma_f32_16x16x32_bf16(af[mf], wf[0][nf], accR[mf][nf], 0, 0, 0);
                        accZ[mf][nf] = __builtin_amdgcn_mfma_f32_16x16x32_bf16(af[mf], wf[1][nf], accZ[mf][nf], 0, 0, 0);
                        accH[mf][nf] = __builtin_amdgcn_mfma_f32_16x16x32_bf16(af[mf], wf[2][nf], accH[mf][nf], 0, 0, 0);
                    }
            }
            __builtin_amdgcn_s_setprio(0);
        }
    }

    const int lr4 = g4 * 4;
#pragma unroll
    for (int mf = 0; mf < 4; ++mf)
#pragma unroll
        for (int nf = 0; nf < 2; ++nf) {
            const int col = c0 + wn * 32 + nf * 16 + lc;
            const float br = BG[col], bz = BG[256 + col];
            const float bi = BG[512 + col], bh = BG[768 + col];
#pragma unroll
            for (int j = 0; j < 4; ++j) {
                const long r = brow + wm * 64 + mf * 16 + lr4 + j;
                const float rr = sigf(accR[mf][nf][j] + br);
                const float zz = sigf(accZ[mf][nf][j] + bz);
                const float nn = tanhf(accI[mf][nf][j] + bi + rr * (accH[mf][nf][j] + bh));
                const float hv = bf2f(hb[r * 256 + col]);
                const float g  = (1.f - zz) * nn + zz * hv;
                gout[r * 256 + col] = g;
                actout[r * 256 + col] = f2bf(g);
            }
        }
}

// ---------------- head GEMM: tanh(g3 @ Wout^T + b) -> d_out[:, :40] ----------
constexpr int BM = 128, BN = 128, BK = 64;

__launch_bounds__(256, 2)
__global__ void head_gemm(const unsigned short* __restrict__ A,
                          const unsigned short* __restrict__ W,
                          const float* __restrict__ bias,
                          float* __restrict__ outp)
{
    __shared__ __align__(16) unsigned short sA[BM * BK];
    __shared__ __align__(16) unsigned short sB[BN * BK];

    const int tid  = threadIdx.x;
    const int lane = tid & 63;
    const int wid  = tid >> 6;
    const int wm   = wid >> 1, wn = wid & 1;
    const long brow = (long)blockIdx.x * BM;

    f32x4 acc[4][4];
#pragma unroll
    for (int i = 0; i < 4; i++)
#pragma unroll
        for (int j = 0; j < 4; j++) acc[i][j] = (f32x4){0.f,0.f,0.f,0.f};

    for (int kt = 0; kt < 4; ++kt) {
        const long k0 = (long)kt * BK;
#pragma unroll
        for (int i = 0; i < 4; i++) {
            const int cb = i * 256 + wid * 64;
            const int c  = cb + lane;
            const int row = c >> 3, seg = c & 7;
            const unsigned short* ga = A + (brow + row) * 256 + k0 + seg * 8;
            const unsigned short* gw = W + (long)row * 256 + k0 + seg * 8;
            __builtin_amdgcn_global_load_lds(
                (const __attribute__((address_space(1))) void*)ga,
                (__attribute__((address_space(3))) void*)(sA + (size_t)cb * 8), 16, 0, 0);
            __builtin_amdgcn_global_load_lds(
                (const __attribute__((address_space(1))) void*)gw,
                (__attribute__((address_space(3))) void*)(sB + (size_t)cb * 8), 16, 0, 0);
        }
        __syncthreads();
#pragma unroll
        for (int kk = 0; kk < 2; ++kk) {
            bf16x8 af[4], bfr[4];
#pragma unroll
            for (int mf = 0; mf < 4; ++mf)
                af[mf] = *(const bf16x8*)&sA[(wm * 64 + mf * 16 + (lane & 15)) * BK + kk * 32 + (lane >> 4) * 8];
#pragma unroll
            for (int nf = 0; nf < 4; ++nf)
                bfr[nf] = *(const bf16x8*)&sB[(wn * 64 + nf * 16 + (lane & 15)) * BK + kk * 32 + (lane >> 4) * 8];
#pragma unroll
            for (int mf = 0; mf < 4; ++mf)
#pragma unroll
                for (int nf = 0; nf < 4; ++nf)
                    acc[mf][nf] = __builtin_amdgcn_mfma_f32_16x16x32_bf16(af[mf], bfr[nf], acc[mf][nf], 0, 0, 0);
        }
        __syncthreads();
    }

    const int lr4 = (lane >> 4) * 4;
    const int lc  = lane & 15;
#pragma unroll
    for (int mf = 0; mf < 4; ++mf)
#pragma unroll
        for (int nf = 0; nf < 4; ++nf) {
            const int n = wn * 64 + nf * 16 + lc;
            const float bs = bias[n];
            f32x4 v = acc[mf][nf];
#pragma unroll
            for (int j = 0; j < 4; ++j) {
                const long r = brow + wm * 64 + mf * 16 + lr4 + j;
                if (n < Ss) outp[r * Ss + n] = tanhf(v[j] + bs);
            }
        }
}

// ---------------- host launch ----------------
extern "C" void kernel_launch(void* const* d_in, const int* in_sizes, int n_in,
                              void* d_out, int out_size, void* d_ws, size_t ws_size,
                              hipStream_t stream)
{
    const float* cond  = (const float*)d_in[0];
    const float* prev  = (const float*)d_in[1];
    const float* h1    = (const float*)d_in[2];
    const float* h2    = (const float*)d_in[3];
    const float* h3    = (const float*)d_in[4];
    const float* w_d1  = (const float*)d_in[5];
    const float* b_d1  = (const float*)d_in[6];
    const float* w_d2  = (const float*)d_in[7];
    const float* b_d2  = (const float*)d_in[8];
    const float* w_ih1 = (const float*)d_in[9];
    const float* w_hh1 = (const float*)d_in[10];
    const float* b_ih1 = (const float*)d_in[11];
    const float* b_hh1 = (const float*)d_in[12];
    const float* w_ih2 = (const float*)d_in[13];
    const float* w_hh2 = (const float*)d_in[14];
    const float* b_ih2 = (const float*)d_in[15];
    const float* b_hh2 = (const float*)d_in[16];
    const float* w_ih3 = (const float*)d_in[17];
    const float* w_hh3 = (const float*)d_in[18];
    const float* b_ih3 = (const float*)d_in[19];
    const float* b_hh3 = (const float*)d_in[20];
    const float* w_out = (const float*)d_in[21];
    const float* b_out = (const float*)d_in[22];

    char* ws = (char*)d_ws;
    float* out_f = (float*)d_out;

    // 1) prep (h->bf16 streaming + weights + biases, ~91MB @ ~6.5TB/s)
    {
        long blocks = (U_TOT + 255) / 256;
        prep_w<<<dim3((unsigned)blocks), dim3(256), 0, stream>>>(
            h1, h2, h3,
            w_d1, b_d1, w_d2, b_d2,
            w_ih1, w_hh1, b_ih1, b_hh1, w_ih2, w_hh2, b_ih2, b_hh2,
            w_ih3, w_hh3, b_ih3, b_hh3, w_out, b_out, ws);
    }

    // 2) dense1 (pure GEMM)
    d1_gemm<<<dim3(Bq / 256, 4), dim3(512), 0, stream>>>(
        cond, prev,
        (const unsigned short*)(ws + O_W1P), (const float*)(ws + O_BD1),
        (unsigned short*)(ws + O_T1));

    // 3) dense2
    d2_gemm<<<dim3(Bq / 256, 4), dim3(512), 0, stream>>>(
        (const unsigned short*)(ws + O_T1),
        (const unsigned short*)(ws + O_W2P), (const float*)(ws + O_BD2),
        (unsigned short*)(ws + O_XMLP));

    // 4) fused GRUs
    const size_t OX[3]   = { O_XMLP, O_GB1, O_GB2 };
    const size_t OHB[3]  = { O_HB1, O_HB2, O_HB3 };
    const size_t OW[3]   = { O_WGF1, O_WGF2, O_WGF3 };
    const size_t OB[3]   = { O_BG1, O_BG2, O_BG3 };
    const size_t GOFF[3] = { GO_G1, GO_G2, GO_G3 };
    const size_t OGB[3]  = { O_GB1, O_GB2, O_GB3 };

    for (int g = 0; g < 3; ++g) {
        gru_fused<<<dim3(Bq / 256, 4), dim3(512), 0, stream>>>(
            (const unsigned short*)(ws + OX[g]), (const unsigned short*)(ws + OHB[g]),
            (const unsigned short*)(ws + OW[g]), (const float*)(ws + OB[g]),
            out_f + GOFF[g], (unsigned short*)(ws + OGB[g]));
    }

    // 5) output head
    head_gemm<<<dim3(Bq / BM), dim3(256), 0, stream>>>(
        (const unsigned short*)(ws + O_GB3), (const unsigned short*)(ws + O_WOUT),
        (const float*)(ws + O_BOUT), out_f + GO_OUT);

    (void)in_sizes; (void)n_in; (void)out_size; (void)ws_size;
}

// Round 15
// 129.745 us; speedup vs baseline: 1.0150x; 1.0150x over previous
//
#include <hip/hip_runtime.h>
#include <hip/hip_bf16.h>

// ---------------- problem constants ----------------
constexpr int Bq = 16384;   // batch
constexpr int Cc = 256;     // hidden
constexpr int Ss = 40;      // prev/out width
constexpr int KD1 = 320;    // 296 padded to 320

// ---------------- ws layout (bytes) ----------------
constexpr size_t O_WD1  = 0;          // bf16 [256][320]  160KB
constexpr size_t O_WD2  = 0x30000;    // bf16 [256][256]  128KB
constexpr size_t O_WOUT = 0x50000;    // bf16 [128][256]  64KB
constexpr size_t O_WGF1 = 0x60000;    // bf16 packed-swizzled gate W, 768KB
constexpr size_t O_WGF2 = 0x120000;
constexpr size_t O_WGF3 = 0x1E0000;
constexpr size_t O_BD1  = 0x2A0000;   // f32 [256]
constexpr size_t O_BD2  = 0x2A0400;   // f32 [256]
constexpr size_t O_BOUT = 0x2A0800;   // f32 [128] (pad 0)
constexpr size_t O_BG1  = 0x2A1000;   // f32 [1024]: [0..511]=b_ih+b_hh (r,z), [512..767]=b_ih_n, [768..1023]=b_hh_n
constexpr size_t O_BG2  = 0x2A2000;
constexpr size_t O_BG3  = 0x2A3000;
constexpr size_t O_XMLP = 0x2B0000;   // bf16 [B][256] 8MB (dense2 out)
constexpr size_t O_GB1  = 0xAB0000;   // bf16 [B][256]  (g1)
constexpr size_t O_GB2  = 0x12B0000;  // bf16 [B][256]  (g2)
constexpr size_t O_GB3  = 0x1AB0000;  // bf16 [B][256]  (g3, head input)
constexpr size_t O_HB1  = 0x22B0000;  // bf16 [B][256]  (h bf16, written by mlp)
constexpr size_t O_HB2  = 0x2AB0000;
constexpr size_t O_HB3  = 0x32B0000;

// d_out element offsets (fp32): out[B,40], g1[B,256], g2, g3
constexpr size_t GO_OUT = 0;
constexpr size_t GO_G1  = (size_t)Bq * Ss;
constexpr size_t GO_G2  = GO_G1 + (size_t)Bq * Cc;
constexpr size_t GO_G3  = GO_G2 + (size_t)Bq * Cc;

typedef __attribute__((ext_vector_type(8))) short bf16x8;
typedef __attribute__((ext_vector_type(4))) float f32x4;

__device__ __forceinline__ float bf2f(unsigned short h) {
    union { unsigned u; float f; } v; v.u = ((unsigned)h) << 16; return v.f;
}
__device__ __forceinline__ unsigned short f2bf(float f) {
    union { float f; unsigned u; } v; v.f = f;
    unsigned u = v.u;
    return (unsigned short)((u + 0x7FFFu + ((u >> 16) & 1u)) >> 16);
}
__device__ __forceinline__ float sigf(float x) { return 1.f / (1.f + __expf(-x)); }

__device__ __forceinline__ bf16x8 cvt8(const float* __restrict__ s) {
    float4 a = *(const float4*)s;
    float4 b = *(const float4*)(s + 4);
    bf16x8 o;
    o[0] = (short)f2bf(a.x); o[1] = (short)f2bf(a.y);
    o[2] = (short)f2bf(a.z); o[3] = (short)f2bf(a.w);
    o[4] = (short)f2bf(b.x); o[5] = (short)f2bf(b.y);
    o[6] = (short)f2bf(b.z); o[7] = (short)f2bf(b.w);
    return o;
}

// ---------------- prep: weights + biases only ----------------
// Gate W packed layout (per GRU), unit = 8 elems:
//   vv = ((((by64*8 + kt)*3 + s)*64 + wrow)*8 + sseg)
//   holds W rows n = s*256 + by64*64 + wrow,
//   k = kt*64 + ((sseg ^ (wrow&7))<<3)      (XOR-swizzled k-chunk)
constexpr long NW1  = 256L * 320;
constexpr long NW2  = 256L * 256;
constexpr long NWGF = 768L * 512;            // per GRU
constexpr long NWO  = 128L * 256;
constexpr long NBIA = 256 + 256 + 128 + 3L * 1024;  // 3712

constexpr long U_W1 = NW1 / 8;
constexpr long U_W2 = NW2 / 8;
constexpr long U_WG = 3 * NWGF / 8;
constexpr long U_WO = NWO / 8;
constexpr long U_B  = (NBIA + 7) / 8;
constexpr long U_TOT = U_W1 + U_W2 + U_WG + U_WO + U_B;

__global__ void prep_w(
    const float* __restrict__ w_d1, const float* __restrict__ b_d1,
    const float* __restrict__ w_d2, const float* __restrict__ b_d2,
    const float* __restrict__ w_ih1, const float* __restrict__ w_hh1,
    const float* __restrict__ b_ih1, const float* __restrict__ b_hh1,
    const float* __restrict__ w_ih2, const float* __restrict__ w_hh2,
    const float* __restrict__ b_ih2, const float* __restrict__ b_hh2,
    const float* __restrict__ w_ih3, const float* __restrict__ w_hh3,
    const float* __restrict__ b_ih3, const float* __restrict__ b_hh3,
    const float* __restrict__ w_out, const float* __restrict__ b_out,
    char* __restrict__ ws)
{
    long v = (long)blockIdx.x * blockDim.x + threadIdx.x;
    if (v >= U_TOT) return;
    if (v < U_W1) {  // Wd1 [256][320] <- [256][296] + pad
        long e = v * 8;
        int k = (int)(e % KD1), n = (int)(e / KD1);
        bf16x8 o = {0,0,0,0,0,0,0,0};
        if (k < 296) o = cvt8(w_d1 + (long)n * 296 + k);
        *(bf16x8*)((unsigned short*)(ws + O_WD1) + e) = o;
        return;
    }
    v -= U_W1;
    if (v < U_W2) {
        long e = v * 8;
        *(bf16x8*)((unsigned short*)(ws + O_WD2) + e) = cvt8(w_d2 + e);
        return;
    }
    v -= U_W2;
    if (v < U_WG) {  // packed-swizzled gate weights
        int g = (int)(v / (NWGF / 8)); long vv = v % (NWGF / 8);
        int sseg = (int)(vv & 7);
        int wrow = (int)((vv >> 3) & 63);
        long q = vv >> 9;
        int s = (int)(q % 3);
        long p = q / 3;
        int ktt = (int)(p & 7), by64 = (int)(p >> 3);
        int n = s * 256 + by64 * 64 + wrow;
        int k = ktt * 64 + ((sseg ^ (wrow & 7)) << 3);
        const float* wih = (g == 0) ? w_ih1 : (g == 1) ? w_ih2 : w_ih3;
        const float* whh = (g == 0) ? w_hh1 : (g == 1) ? w_hh2 : w_hh3;
        size_t off = (g == 0) ? O_WGF1 : (g == 1) ? O_WGF2 : O_WGF3;
        const float* src = (k < 256) ? (wih + (long)n * 256 + k)
                                     : (whh + (long)n * 256 + (k - 256));
        *(bf16x8*)((unsigned short*)(ws + off) + vv * 8) = cvt8(src);
        return;
    }
    v -= U_WG;
    if (v < U_WO) {  // Wout [128][256], rows >= 40 zero
        long e = v * 8;
        int n = (int)(e / 256);
        bf16x8 o = {0,0,0,0,0,0,0,0};
        if (n < Ss) o = cvt8(w_out + e);
        *(bf16x8*)((unsigned short*)(ws + O_WOUT) + e) = o;
        return;
    }
    v -= U_WO;
    {   // biases, scalar
        long ebase = v * 8;
#pragma unroll
        for (int t = 0; t < 8; ++t) {
            long j = ebase + t;
            if (j >= NBIA) break;
            if (j < 256) { ((float*)(ws + O_BD1))[j] = b_d1[j]; continue; }
            long j2 = j - 256;
            if (j2 < 256) { ((float*)(ws + O_BD2))[j2] = b_d2[j2]; continue; }
            j2 -= 256;
            if (j2 < 128) { ((float*)(ws + O_BOUT))[j2] = (j2 < Ss) ? b_out[j2] : 0.f; continue; }
            j2 -= 128;
            int g = (int)(j2 / 1024); int jj = (int)(j2 % 1024);
            const float* bih = (g == 0) ? b_ih1 : (g == 1) ? b_ih2 : b_ih3;
            const float* bhh = (g == 0) ? b_hh1 : (g == 1) ? b_hh2 : b_hh3;
            float* dst = (float*)(ws + ((g == 0) ? O_BG1 : (g == 1) ? O_BG2 : O_BG3));
            float val;
            if (jj < 512)      val = bih[jj] + bhh[jj];
            else if (jj < 768) val = bih[jj];           // b_ih_n
            else               val = bhh[jj - 256];     // b_hh_n
            dst[jj] = val;
        }
    }
}

// ---------------- fused MLP + h->bf16 conversion ----------------
__launch_bounds__(256, 2)
__global__ void mlp_fused(const float* __restrict__ cond,
                          const float* __restrict__ prev,
                          const float* __restrict__ h1,
                          const float* __restrict__ h2,
                          const float* __restrict__ h3,
                          const unsigned short* __restrict__ W1,
                          const float* __restrict__ B1,
                          const unsigned short* __restrict__ W2,
                          const float* __restrict__ B2,
                          unsigned short* __restrict__ xout,
                          unsigned short* __restrict__ hb1,
                          unsigned short* __restrict__ hb2,
                          unsigned short* __restrict__ hb3)
{
    __shared__ __align__(16) unsigned short sX[32 * 64];    // 4KB
    __shared__ __align__(16) unsigned short sW[256 * 64];   // 32KB
    __shared__ __align__(16) unsigned short sT[32 * 264];   // 16.5KB, padded stride

    const int tid  = threadIdx.x;
    const int lane = tid & 63;
    const int wid  = tid >> 6;
    const long brow = (long)blockIdx.x * 32;
    const int lr4 = (lane >> 4) * 4;
    const int lc  = lane & 15;

    // ---- h -> bf16 for this block's 32 rows (4 chunks/thread/tensor) ----
    {
        const long base = brow * 256;
#pragma unroll
        for (int i = 0; i < 4; ++i) {
            const long q = (long)(i * 256 + tid) * 8;
            *(bf16x8*)(hb1 + base + q) = cvt8(h1 + base + q);
        }
#pragma unroll
        for (int i = 0; i < 4; ++i) {
            const long q = (long)(i * 256 + tid) * 8;
            *(bf16x8*)(hb2 + base + q) = cvt8(h2 + base + q);
        }
#pragma unroll
        for (int i = 0; i < 4; ++i) {
            const long q = (long)(i * 256 + tid) * 8;
            *(bf16x8*)(hb3 + base + q) = cvt8(h3 + base + q);
        }
    }

    f32x4 acc[2][4];
#pragma unroll
    for (int i = 0; i < 2; i++)
#pragma unroll
        for (int j = 0; j < 4; j++) acc[i][j] = (f32x4){0.f,0.f,0.f,0.f};

    // ---- dense1: K=320 ----
    for (int kt = 0; kt < 5; ++kt) {
        const int k0 = kt * 64;
        {
            const int row = tid >> 3, cs = (tid & 7) * 8;
            bf16x8 o;
            if (kt < 4) {
                o = cvt8(cond + (brow + row) * 256 + k0 + cs);
            } else {
#pragma unroll
                for (int e = 0; e < 8; ++e) {
                    int col = 256 + cs + e;
                    float vv = (col < 296) ? prev[(brow + row) * Ss + (col - 256)] : 0.f;
                    o[e] = (short)f2bf(vv);
                }
            }
            *(bf16x8*)(sX + row * 64 + cs) = o;
        }
#pragma unroll
        for (int i = 0; i < 8; ++i) {
            const int cb = i * 256 + wid * 64;
            const int c  = cb + lane;
            const int row = c >> 3, seg = c & 7;
            const unsigned short* gw = W1 + (long)row * KD1 + k0 + seg * 8;
            __builtin_amdgcn_global_load_lds(
                (const __attribute__((address_space(1))) void*)gw,
                (__attribute__((address_space(3))) void*)(sW + (size_t)cb * 8), 16, 0, 0);
        }
        __syncthreads();
#pragma unroll
        for (int kk = 0; kk < 2; ++kk) {
            bf16x8 af[2], wf[4];
#pragma unroll
            for (int mf = 0; mf < 2; ++mf)
                af[mf] = *(const bf16x8*)&sX[(mf * 16 + lc) * 64 + kk * 32 + (lane >> 4) * 8];
#pragma unroll
            for (int nf = 0; nf < 4; ++nf)
                wf[nf] = *(const bf16x8*)&sW[(wid * 64 + nf * 16 + lc) * 64 + kk * 32 + (lane >> 4) * 8];
#pragma unroll
            for (int mf = 0; mf < 2; ++mf)
#pragma unroll
                for (int nf = 0; nf < 4; ++nf)
                    acc[mf][nf] = __builtin_amdgcn_mfma_f32_16x16x32_bf16(af[mf], wf[nf], acc[mf][nf], 0, 0, 0);
        }
        __syncthreads();
    }
    // epilogue1 -> sT
#pragma unroll
    for (int mf = 0; mf < 2; ++mf)
#pragma unroll
        for (int nf = 0; nf < 4; ++nf) {
            const int col = wid * 64 + nf * 16 + lc;
            const float bs = B1[col];
#pragma unroll
            for (int j = 0; j < 4; ++j) {
                const int row = mf * 16 + lr4 + j;
                sT[row * 264 + col] = f2bf(tanhf(acc[mf][nf][j] + bs));
            }
            acc[mf][nf] = (f32x4){0.f,0.f,0.f,0.f};
        }

    // ---- dense2: K=256, A = sT ----
    for (int kt = 0; kt < 4; ++kt) {
        const int k0 = kt * 64;
#pragma unroll
        for (int i = 0; i < 8; ++i) {
            const int cb = i * 256 + wid * 64;
            const int c  = cb + lane;
            const int row = c >> 3, seg = c & 7;
            const unsigned short* gw = W2 + (long)row * 256 + k0 + seg * 8;
            __builtin_amdgcn_global_load_lds(
                (const __attribute__((address_space(1))) void*)gw,
                (__attribute__((address_space(3))) void*)(sW + (size_t)cb * 8), 16, 0, 0);
        }
        __syncthreads();
#pragma unroll
        for (int kk = 0; kk < 2; ++kk) {
            bf16x8 af[2], wf[4];
#pragma unroll
            for (int mf = 0; mf < 2; ++mf)
                af[mf] = *(const bf16x8*)&sT[(mf * 16 + lc) * 264 + k0 + kk * 32 + (lane >> 4) * 8];
#pragma unroll
            for (int nf = 0; nf < 4; ++nf)
                wf[nf] = *(const bf16x8*)&sW[(wid * 64 + nf * 16 + lc) * 64 + kk * 32 + (lane >> 4) * 8];
#pragma unroll
            for (int mf = 0; mf < 2; ++mf)
#pragma unroll
                for (int nf = 0; nf < 4; ++nf)
                    acc[mf][nf] = __builtin_amdgcn_mfma_f32_16x16x32_bf16(af[mf], wf[nf], acc[mf][nf], 0, 0, 0);
        }
        __syncthreads();
    }
#pragma unroll
    for (int mf = 0; mf < 2; ++mf)
#pragma unroll
        for (int nf = 0; nf < 4; ++nf) {
            const int col = wid * 64 + nf * 16 + lc;
            const float bs = B2[col];
#pragma unroll
            for (int j = 0; j < 4; ++j) {
                const long r = brow + mf * 16 + lr4 + j;
                xout[r * 256 + col] = f2bf(tanhf(acc[mf][nf][j] + bs));
            }
        }
}

// ---------------- fused GRU v7: 512 threads, 3-deep W / 2-deep A pipeline ---
__launch_bounds__(512, 1)
__global__ void gru_fused(const unsigned short* __restrict__ x,
                          const unsigned short* __restrict__ hb,
                          const unsigned short* __restrict__ PW,
                          const float* __restrict__ BG,
                          float* __restrict__ gout,
                          unsigned short* __restrict__ actout)
{
    __shared__ __align__(16) unsigned short sA[2][256 * 64];     // 2 x 32KB
    __shared__ __align__(16) unsigned short sW[3][3 * 64 * 64];  // 3 x 24KB

    const int tid  = threadIdx.x;
    const int lane = tid & 63;
    const int wid  = tid >> 6;        // 0..7
    const int wm   = wid >> 1;        // 0..3: 64-row strip
    const int wn   = wid & 1;         // 0..1: 32-col half
    const int g4   = lane >> 4;       // 0..3 (k-segment group)
    const int lc   = lane & 15;
    const long brow = (long)blockIdx.x * 256;
    const int  by   = blockIdx.y;     // col block (64 cols)
    const int  c0   = by * 64;

    f32x4 accR[4][2], accZ[4][2], accI[4][2], accH[4][2];
#pragma unroll
    for (int i = 0; i < 4; i++)
#pragma unroll
        for (int j = 0; j < 2; j++) {
            accR[i][j] = (f32x4){0.f,0.f,0.f,0.f};
            accZ[i][j] = (f32x4){0.f,0.f,0.f,0.f};
            accI[i][j] = (f32x4){0.f,0.f,0.f,0.f};
            accH[i][j] = (f32x4){0.f,0.f,0.f,0.f};
        }

    auto stage_a = [&](int buf, int kt) {
        const unsigned short* src = (kt < 4) ? x : hb;
        const int kc0 = (kt & 3) * 64;
#pragma unroll
        for (int i = 0; i < 4; ++i) {
            const int c = i * 512 + tid;        // 16B chunk index, 0..2047
            const int row = c >> 3;
            const int kcol = ((c & 7) ^ (row & 7)) << 3;
            const unsigned short* ga = src + (brow + row) * 256 + kc0 + kcol;
            __builtin_amdgcn_global_load_lds(
                (const __attribute__((address_space(1))) void*)ga,
                (__attribute__((address_space(3))) void*)(&sA[buf][0] + (size_t)c * 8), 16, 0, 0);
        }
    };
    auto stage_w = [&](int buf, int kt) {
        const unsigned short* Wbase = PW + (size_t)(by * 8 + kt) * 12288;
#pragma unroll
        for (int i = 0; i < 3; ++i) {
            const int c = i * 512 + tid;        // 0..1535
            const unsigned short* gw = Wbase + (size_t)c * 8;
            __builtin_amdgcn_global_load_lds(
                (const __attribute__((address_space(1))) void*)gw,
                (__attribute__((address_space(3))) void*)(&sW[buf][0] + (size_t)c * 8), 16, 0, 0);
        }
    };

    // prologue: W0, A0, W1 in flight (10 loads/thread)
    stage_w(0, 0);
    stage_a(0, 0);
    stage_w(1, 1);

#pragma unroll
    for (int kt = 0; kt < 8; ++kt) {
        if (kt < 7) asm volatile("s_waitcnt vmcnt(3)" ::: "memory");
        else        asm volatile("s_waitcnt vmcnt(0)" ::: "memory");
        __builtin_amdgcn_s_barrier();
        __builtin_amdgcn_sched_barrier(0);

        if (kt + 1 < 8) stage_a((kt + 1) & 1, kt + 1);
        if (kt + 2 < 8) stage_w((kt + 2) % 3, kt + 2);

        const int ab = kt & 1, wb = kt % 3;
#pragma unroll
        for (int kk = 0; kk < 2; ++kk) {
            bf16x8 af[4], wf[3][2];
#pragma unroll
            for (int mf = 0; mf < 4; ++mf) {
                const int row = wm * 64 + mf * 16 + lc;
                const int chunk = row * 8 + ((kk * 4 + g4) ^ (row & 7));
                af[mf] = *(const bf16x8*)&sA[ab][chunk * 8];
            }
#pragma unroll
            for (int s = 0; s < 3; ++s)
#pragma unroll
                for (int nf = 0; nf < 2; ++nf) {
                    const int wrow = wn * 32 + nf * 16 + lc;
                    const int chunk = s * 512 + wrow * 8 + ((kk * 4 + g4) ^ (wrow & 7));
                    wf[s][nf] = *(const bf16x8*)&sW[wb][chunk * 8];
                }
            __builtin_amdgcn_s_setprio(1);
            if (kt < 4) {
#pragma unroll
                for (int mf = 0; mf < 4; ++mf)
#pragma unroll
                    for (int nf = 0; nf < 2; ++nf) {
                        accR[mf][nf] = __builtin_amdgcn_mfma_f32_16x16x32_bf16(af[mf], wf[0][nf], accR[mf][nf], 0, 0, 0);
                        accZ[mf][nf] = __builtin_amdgcn_mfma_f32_16x16x32_bf16(af[mf], wf[1][nf], accZ[mf][nf], 0, 0, 0);
                        accI[mf][nf] = __builtin_amdgcn_mfma_f32_16x16x32_bf16(af[mf], wf[2][nf], accI[mf][nf], 0, 0, 0);
                    }
            } else {
#pragma unroll
                for (int mf = 0; mf < 4; ++mf)
#pragma unroll
                    for (int nf = 0; nf < 2; ++nf) {
                        accR[mf][nf] = __builtin_amdgcn_mfma_f32_16x16x32_bf16(af[mf], wf[0][nf], accR[mf][nf], 0, 0, 0);
                        accZ[mf][nf] = __builtin_amdgcn_mfma_f32_16x16x32_bf16(af[mf], wf[1][nf], accZ[mf][nf], 0, 0, 0);
                        accH[mf][nf] = __builtin_amdgcn_mfma_f32_16x16x32_bf16(af[mf], wf[2][nf], accH[mf][nf], 0, 0, 0);
                    }
            }
            __builtin_amdgcn_s_setprio(0);
        }
    }

    // epilogue: GRU cell; C/D layout col=lane&15, row=(lane>>4)*4+j
    const int lr4 = g4 * 4;
#pragma unroll
    for (int mf = 0; mf < 4; ++mf)
#pragma unroll
        for (int nf = 0; nf < 2; ++nf) {
            const int col = c0 + wn * 32 + nf * 16 + lc;
            const float br = BG[col], bz = BG[256 + col];
            const float bi = BG[512 + col], bh = BG[768 + col];
#pragma unroll
            for (int j = 0; j < 4; ++j) {
                const long r = brow + wm * 64 + mf * 16 + lr4 + j;
                const float rr = sigf(accR[mf][nf][j] + br);
                const float zz = sigf(accZ[mf][nf][j] + bz);
                const float nn = tanhf(accI[mf][nf][j] + bi + rr * (accH[mf][nf][j] + bh));
                const float hv = bf2f(hb[r * 256 + col]);
                const float g  = (1.f - zz) * nn + zz * hv;
                gout[r * 256 + col] = g;
                actout[r * 256 + col] = f2bf(g);
            }
        }
}

// ---------------- head GEMM: tanh(g3 @ Wout^T + b) -> d_out[:, :40] ----------
constexpr int BM = 128, BN = 128, BK = 64;

__launch_bounds__(256, 2)
__global__ void head_gemm(const unsigned short* __restrict__ A,
                          const unsigned short* __restrict__ W,
                          const float* __restrict__ bias,
                          float* __restrict__ outp)
{
    __shared__ __align__(16) unsigned short sA[BM * BK];
    __shared__ __align__(16) unsigned short sB[BN * BK];

    const int tid  = threadIdx.x;
    const int lane = tid & 63;
    const int wid  = tid >> 6;
    const int wm   = wid >> 1, wn = wid & 1;
    const long brow = (long)blockIdx.x * BM;

    f32x4 acc[4][4];
#pragma unroll
    for (int i = 0; i < 4; i++)
#pragma unroll
        for (int j = 0; j < 4; j++) acc[i][j] = (f32x4){0.f,0.f,0.f,0.f};

    for (int kt = 0; kt < 4; ++kt) {
        const long k0 = (long)kt * BK;
#pragma unroll
        for (int i = 0; i < 4; i++) {
            const int cb = i * 256 + wid * 64;
            const int c  = cb + lane;
            const int row = c >> 3, seg = c & 7;
            const unsigned short* ga = A + (brow + row) * 256 + k0 + seg * 8;
            const unsigned short* gw = W + (long)row * 256 + k0 + seg * 8;
            __builtin_amdgcn_global_load_lds(
                (const __attribute__((address_space(1))) void*)ga,
                (__attribute__((address_space(3))) void*)(sA + (size_t)cb * 8), 16, 0, 0);
            __builtin_amdgcn_global_load_lds(
                (const __attribute__((address_space(1))) void*)gw,
                (__attribute__((address_space(3))) void*)(sB + (size_t)cb * 8), 16, 0, 0);
        }
        __syncthreads();
#pragma unroll
        for (int kk = 0; kk < 2; ++kk) {
            bf16x8 af[4], bfr[4];
#pragma unroll
            for (int mf = 0; mf < 4; ++mf)
                af[mf] = *(const bf16x8*)&sA[(wm * 64 + mf * 16 + (lane & 15)) * BK + kk * 32 + (lane >> 4) * 8];
#pragma unroll
            for (int nf = 0; nf < 4; ++nf)
                bfr[nf] = *(const bf16x8*)&sB[(wn * 64 + nf * 16 + (lane & 15)) * BK + kk * 32 + (lane >> 4) * 8];
#pragma unroll
            for (int mf = 0; mf < 4; ++mf)
#pragma unroll
                for (int nf = 0; nf < 4; ++nf)
                    acc[mf][nf] = __builtin_amdgcn_mfma_f32_16x16x32_bf16(af[mf], bfr[nf], acc[mf][nf], 0, 0, 0);
        }
        __syncthreads();
    }

    const int lr4 = (lane >> 4) * 4;
    const int lc  = lane & 15;
#pragma unroll
    for (int mf = 0; mf < 4; ++mf)
#pragma unroll
        for (int nf = 0; nf < 4; ++nf) {
            const int n = wn * 64 + nf * 16 + lc;
            const float bs = bias[n];
            f32x4 v = acc[mf][nf];
#pragma unroll
            for (int j = 0; j < 4; ++j) {
                const long r = brow + wm * 64 + mf * 16 + lr4 + j;
                if (n < Ss) outp[r * Ss + n] = tanhf(v[j] + bs);
            }
        }
}

// ---------------- host launch ----------------
extern "C" void kernel_launch(void* const* d_in, const int* in_sizes, int n_in,
                              void* d_out, int out_size, void* d_ws, size_t ws_size,
                              hipStream_t stream)
{
    const float* cond  = (const float*)d_in[0];
    const float* prev  = (const float*)d_in[1];
    const float* h1    = (const float*)d_in[2];
    const float* h2    = (const float*)d_in[3];
    const float* h3    = (const float*)d_in[4];
    const float* w_d1  = (const float*)d_in[5];
    const float* b_d1  = (const float*)d_in[6];
    const float* w_d2  = (const float*)d_in[7];
    const float* b_d2  = (const float*)d_in[8];
    const float* w_ih1 = (const float*)d_in[9];
    const float* w_hh1 = (const float*)d_in[10];
    const float* b_ih1 = (const float*)d_in[11];
    const float* b_hh1 = (const float*)d_in[12];
    const float* w_ih2 = (const float*)d_in[13];
    const float* w_hh2 = (const float*)d_in[14];
    const float* b_ih2 = (const float*)d_in[15];
    const float* b_hh2 = (const float*)d_in[16];
    const float* w_ih3 = (const float*)d_in[17];
    const float* w_hh3 = (const float*)d_in[18];
    const float* b_ih3 = (const float*)d_in[19];
    const float* b_hh3 = (const float*)d_in[20];
    const float* w_out = (const float*)d_in[21];
    const float* b_out = (const float*)d_in[22];

    char* ws = (char*)d_ws;
    float* out_f = (float*)d_out;

    // 1) prep (weights + biases only, ~19MB)
    {
        long blocks = (U_TOT + 255) / 256;
        prep_w<<<dim3((unsigned)blocks), dim3(256), 0, stream>>>(
            w_d1, b_d1, w_d2, b_d2,
            w_ih1, w_hh1, b_ih1, b_hh1, w_ih2, w_hh2, b_ih2, b_hh2,
            w_ih3, w_hh3, b_ih3, b_hh3, w_out, b_out, ws);
    }

    // 2) fused MLP + h->bf16 conversion
    mlp_fused<<<dim3(Bq / 32), dim3(256), 0, stream>>>(
        cond, prev, h1, h2, h3,
        (const unsigned short*)(ws + O_WD1), (const float*)(ws + O_BD1),
        (const unsigned short*)(ws + O_WD2), (const float*)(ws + O_BD2),
        (unsigned short*)(ws + O_XMLP),
        (unsigned short*)(ws + O_HB1), (unsigned short*)(ws + O_HB2),
        (unsigned short*)(ws + O_HB3));

    // 3) fused GRUs (R9 v7 pipeline, hb bf16)
    const size_t OX[3]   = { O_XMLP, O_GB1, O_GB2 };
    const size_t OHB[3]  = { O_HB1, O_HB2, O_HB3 };
    const size_t OW[3]   = { O_WGF1, O_WGF2, O_WGF3 };
    const size_t OB[3]   = { O_BG1, O_BG2, O_BG3 };
    const size_t GOFF[3] = { GO_G1, GO_G2, GO_G3 };
    const size_t OGB[3]  = { O_GB1, O_GB2, O_GB3 };

    for (int g = 0; g < 3; ++g) {
        gru_fused<<<dim3(Bq / 256, 4), dim3(512), 0, stream>>>(
            (const unsigned short*)(ws + OX[g]), (const unsigned short*)(ws + OHB[g]),
            (const unsigned short*)(ws + OW[g]), (const float*)(ws + OB[g]),
            out_f + GOFF[g], (unsigned short*)(ws + OGB[g]));
    }

    // 4) output head
    head_gemm<<<dim3(Bq / BM), dim3(256), 0, stream>>>(
        (const unsigned short*)(ws + O_GB3), (const unsigned short*)(ws + O_WOUT),
        (const float*)(ws + O_BOUT), out_f + GO_OUT);

    (void)in_sizes; (void)n_in; (void)out_size; (void)ws_size;
}